// Round 5
// baseline (798.677 us; speedup 1.0000x reference)
//
#include <hip/hip_runtime.h>
#include <hip/hip_bf16.h>
#include <hip/hip_fp16.h>

#define N_NODES  100000
#define N_HEDGES 50000
#define NNZ      1600000
#define IN_C     128
#define HID_C    128
#define N_CLS    8

#define BE 13   // ceil(N_HEDGES/4096)
#define BN 25   // ceil(N_NODES/4096)

#define NB_DEG ((NNZ + 255) / 256)      // 6250
#define NB_G1  ((N_NODES + 63) / 64)    // 1563
#define NB_MIX (NB_DEG + NB_G1)         // 7813

#define NODE_PLANE_H2  ((size_t)N_NODES * 8)    // half2 per 16-ch node plane
#define HEDGE_PLANE_H2 ((size_t)N_HEDGES * 8)

struct alignas(16) H8 { __half2 h[4]; };

// ---------------- merged (interleaved): degree+rank || GEMM1 (planar fp16 out) ----------------
__global__ __launch_bounds__(256) void k_deg_gemm1(
        const int* __restrict__ nidx, const int* __restrict__ eidx,
        int* __restrict__ deg_n, int* __restrict__ deg_e,
        int* __restrict__ rank_n, int* __restrict__ rank_e,
        const float* __restrict__ X, const float* __restrict__ W,
        __half* __restrict__ XWH) {
    __shared__ float sA[64 * 36];   // stride 36: 2-way LDS aliasing only (free)
    __shared__ float sB[32 * 128];
    const int bid = blockIdx.x;
    const bool is_gemm = (bid % 5 == 2);
    if (!is_gemm) {
        int deg_id = bid - (bid + 2) / 5;
        int i = deg_id * 256 + threadIdx.x;
        if (i < NNZ) {
            rank_n[i] = atomicAdd(&deg_n[nidx[i]], 1);
            rank_e[i] = atomicAdd(&deg_e[eidx[i]], 1);
        }
        return;
    }
    const int gid = (bid + 2) / 5;
    const int tid = threadIdx.x;
    const int row0 = gid * 64;
    const int tx = tid & 15, ty = tid >> 4;

    float acc[4][8];
#pragma unroll
    for (int r = 0; r < 4; r++)
#pragma unroll
        for (int c = 0; c < 8; c++) acc[r][c] = 0.f;

    for (int kt = 0; kt < 128; kt += 32) {
        {
            int idx = tid * 8;
            int ar = idx >> 5, ak = idx & 31;
            int grow = row0 + ar; if (grow >= N_NODES) grow = N_NODES - 1;
            const float4* src = (const float4*)&X[(size_t)grow * 128 + kt + ak];
            float4 v0 = src[0], v1 = src[1];
            *(float4*)&sA[ar * 36 + ak] = v0;
            *(float4*)&sA[ar * 36 + ak + 4] = v1;
        }
        {
            int idx = tid * 16;
            int br = idx >> 7, bc = idx & 127;
            const float4* src = (const float4*)&W[(size_t)(kt + br) * 128 + bc];
            float4 v0 = src[0], v1 = src[1], v2 = src[2], v3 = src[3];
            *(float4*)&sB[br * 128 + bc]      = v0;
            *(float4*)&sB[br * 128 + bc + 4]  = v1;
            *(float4*)&sB[br * 128 + bc + 8]  = v2;
            *(float4*)&sB[br * 128 + bc + 12] = v3;
        }
        __syncthreads();
#pragma unroll
        for (int kk = 0; kk < 32; kk++) {
            float a[4], b[8];
#pragma unroll
            for (int r = 0; r < 4; r++) a[r] = sA[(ty * 4 + r) * 36 + kk];
#pragma unroll
            for (int j = 0; j < 8; j++) b[j] = sB[kk * 128 + tx * 8 + j];
#pragma unroll
            for (int r = 0; r < 4; r++)
#pragma unroll
                for (int j = 0; j < 8; j++) acc[r][j] = fmaf(a[r], b[j], acc[r][j]);
        }
        __syncthreads();
    }
    // planar epilogue: channels [tx*8, tx*8+8) -> plane tx>>1, offset (tx&1)*8
    const int g = tx >> 1;
    __half* plane = XWH + (size_t)g * N_NODES * 16;
#pragma unroll
    for (int r = 0; r < 4; r++) {
        int grow = row0 + ty * 4 + r;
        if (grow < N_NODES) {
            H8 tmp;
            tmp.h[0] = __floats2half2_rn(acc[r][0], acc[r][1]);
            tmp.h[1] = __floats2half2_rn(acc[r][2], acc[r][3]);
            tmp.h[2] = __floats2half2_rn(acc[r][4], acc[r][5]);
            tmp.h[3] = __floats2half2_rn(acc[r][6], acc[r][7]);
            *(H8*)&plane[(size_t)grow * 16 + (tx & 1) * 8] = tmp;
        }
    }
}

// ---------------- hierarchical scan, stage 1 ----------------
__global__ __launch_bounds__(1024) void k_scan1(const int* __restrict__ deg_e, int* __restrict__ off_e,
                                                const int* __restrict__ deg_n, int* __restrict__ off_n,
                                                int* __restrict__ part) {
    int gb = blockIdx.x;
    const int* cnt; int* off; int n; int b; int* ps;
    if (gb < BE) { cnt = deg_e; off = off_e; n = N_HEDGES; b = gb; ps = part; }
    else         { cnt = deg_n; off = off_n; n = N_NODES;  b = gb - BE; ps = part + 32; }
    const int tid = threadIdx.x, lane = tid & 63, wid = tid >> 6;
    int i0 = b * 4096 + tid * 4;
    int v0 = (i0 + 0 < n) ? cnt[i0 + 0] : 0;
    int v1 = (i0 + 1 < n) ? cnt[i0 + 1] : 0;
    int v2 = (i0 + 2 < n) ? cnt[i0 + 2] : 0;
    int v3 = (i0 + 3 < n) ? cnt[i0 + 3] : 0;
    int s = v0 + v1 + v2 + v3;
    int incl = s;
#pragma unroll
    for (int d = 1; d < 64; d <<= 1) {
        int t = __shfl_up(incl, d);
        if (lane >= d) incl += t;
    }
    __shared__ int wsum[16];
    __shared__ int wbase[16];
    if (lane == 63) wsum[wid] = incl;
    __syncthreads();
    if (tid == 0) {
        int r = 0;
#pragma unroll
        for (int k = 0; k < 16; k++) { wbase[k] = r; r += wsum[k]; }
        ps[b] = r;
    }
    __syncthreads();
    int run = wbase[wid] + incl - s;
    if (i0 + 0 < n) { run += v0; off[i0 + 1] = run; }
    if (i0 + 1 < n) { run += v1; off[i0 + 2] = run; }
    if (i0 + 2 < n) { run += v2; off[i0 + 3] = run; }
    if (i0 + 3 < n) { run += v3; off[i0 + 4] = run; }
}

// ---------------- stage 2 ----------------
__global__ void k_scan2(int* __restrict__ part) {
    int t = threadIdx.x;
    if (t == 0) { int r = 0; for (int k = 0; k < BE; k++) { int x = part[k]; part[k] = r; r += x; } }
    if (t == 1) { int r = 0; for (int k = 0; k < BN; k++) { int x = part[32 + k]; part[32 + k] = r; r += x; } }
}

// ---------------- stage 3 ----------------
__global__ __launch_bounds__(1024) void k_scan3(int* __restrict__ off_e, int* __restrict__ off_n,
                                                const int* __restrict__ part) {
    int gb = blockIdx.x;
    int* off; int n; int b; int add;
    if (gb < BE) { off = off_e; n = N_HEDGES; b = gb; add = part[b]; }
    else         { off = off_n; n = N_NODES;  b = gb - BE; add = part[32 + b]; }
    int tid = threadIdx.x;
    int i0 = b * 4096 + tid * 4;
    if (b == 0 && tid == 0) off[0] = 0;
#pragma unroll
    for (int k = 0; k < 4; k++)
        if (i0 + k < n) off[i0 + 1 + k] += add;
}

// ---------------- fill adjacency lists (atomic-free) ----------------
__global__ void k_fill(const int* __restrict__ nidx, const int* __restrict__ eidx,
                       const int* __restrict__ rank_n, const int* __restrict__ rank_e,
                       const int* __restrict__ off_n, const int* __restrict__ off_e,
                       int* __restrict__ list_n, int* __restrict__ list_e) {
    int i = blockIdx.x * blockDim.x + threadIdx.x;
    if (i < NNZ) {
        int v = nidx[i], e = eidx[i];
        list_e[off_e[e] + rank_e[i]] = v;
        list_n[off_n[v] + rank_n[i]] = e;
    }
}

// ---------------- edge gather L1, channel-split planar (XCD-affine) ----------------
// block: plane g = blockIdx&7, 4 waves = 4 edges; wave: 8 slots x 8 lanes (half2 each)
__global__ __launch_bounds__(256) void k_egather1s(const int* __restrict__ off_e,
                                                   const int* __restrict__ list_e,
                                                   const __half2* __restrict__ xw,
                                                   __half2* __restrict__ S) {
    const int g = blockIdx.x & 7;
    const int e = (blockIdx.x >> 3) * 4 + (threadIdx.x >> 6);
    const int lane = threadIdx.x & 63;
    if (e >= N_HEDGES) return;
    const __half2* xp = xw + (size_t)g * NODE_PLANE_H2;
    const int slot = lane >> 3, p = lane & 7;
    int s0 = off_e[e], s1 = off_e[e + 1];
    float ax = 0.f, ay = 0.f;
    for (int base = s0; base < s1; base += 64) {
        int rem = s1 - base;
        int cnt = rem > 64 ? 64 : rem;
        int idx = (lane < cnt) ? __builtin_nontemporal_load(&list_e[base + lane]) : 0;
#pragma unroll 2
        for (int r = 0; r < 64; r += 8) {
            if (r >= cnt) break;
            int u = __shfl(idx, r + slot);
            if (r + slot < cnt) {
                float2 t = __half22float2(xp[(size_t)u * 8 + p]);
                ax += t.x; ay += t.y;
            }
        }
    }
    ax += __shfl_xor(ax, 8);  ay += __shfl_xor(ay, 8);
    ax += __shfl_xor(ax, 16); ay += __shfl_xor(ay, 16);
    ax += __shfl_xor(ax, 32); ay += __shfl_xor(ay, 32);
    float binv = (s1 > s0) ? 1.f / (float)(s1 - s0) : 0.f;
    if (lane < 8) {
        __half2* Sp = S + (size_t)g * HEDGE_PLANE_H2;
        Sp[(size_t)e * 8 + lane] = __floats2half2_rn(ax * binv, ay * binv);
    }
}

// ---------------- node gather L1, channel-split planar (XCD-affine), relu+bias ----------------
__global__ __launch_bounds__(256) void k_ngather1s(const int* __restrict__ off_n,
                                                   const int* __restrict__ list_n,
                                                   const __half2* __restrict__ S,
                                                   const float* __restrict__ b1,
                                                   __half2* __restrict__ H) {
    const int g = blockIdx.x & 7;
    const int v = (blockIdx.x >> 3) * 4 + (threadIdx.x >> 6);
    const int lane = threadIdx.x & 63;
    if (v >= N_NODES) return;
    const __half2* Sp = S + (size_t)g * HEDGE_PLANE_H2;
    const int slot = lane >> 3, p = lane & 7;
    int s0 = off_n[v], s1 = off_n[v + 1];
    float ax = 0.f, ay = 0.f;
    for (int base = s0; base < s1; base += 64) {
        int rem = s1 - base;
        int cnt = rem > 64 ? 64 : rem;
        int idx = (lane < cnt) ? __builtin_nontemporal_load(&list_n[base + lane]) : 0;
#pragma unroll 2
        for (int r = 0; r < 64; r += 8) {
            if (r >= cnt) break;
            int e = __shfl(idx, r + slot);
            if (r + slot < cnt) {
                float2 t = __half22float2(Sp[(size_t)e * 8 + p]);
                ax += t.x; ay += t.y;
            }
        }
    }
    ax += __shfl_xor(ax, 8);  ay += __shfl_xor(ay, 8);
    ax += __shfl_xor(ax, 16); ay += __shfl_xor(ay, 16);
    ax += __shfl_xor(ax, 32); ay += __shfl_xor(ay, 32);
    float dinv = (s1 > s0) ? 1.f / (float)(s1 - s0) : 0.f;
    if (lane < 8) {
        float2 bb = *(const float2*)&b1[g * 16 + lane * 2];
        float h0 = fmaxf(fmaf(ax, dinv, bb.x), 0.f);
        float h1 = fmaxf(fmaf(ay, dinv, bb.y), 0.f);
        __half2* Hp = H + (size_t)g * NODE_PLANE_H2;
        Hp[(size_t)v * 8 + lane] = __floats2half2_rn(h0, h1);
    }
}

// ---------------- GEMM2: wave per node, planar fp16 H read, butterfly ----------------
__global__ __launch_bounds__(256) void k_gemm2w(const __half2* __restrict__ H,
                                                const float* __restrict__ W2,
                                                float* __restrict__ y2) {
    const int v = blockIdx.x * 4 + (threadIdx.x >> 6);
    const int lane = threadIdx.x & 63;
    if (v >= N_NODES) return;
    const int g = lane >> 3, p = lane & 7;
    const int ch = g * 16 + p * 2;
    float wreg[16];
    {
        const float4* wp = (const float4*)&W2[ch * 8];
#pragma unroll
        for (int q = 0; q < 4; q++) {
            float4 t = wp[q];
            wreg[4 * q + 0] = t.x; wreg[4 * q + 1] = t.y;
            wreg[4 * q + 2] = t.z; wreg[4 * q + 3] = t.w;
        }
    }
    float2 h = __half22float2(H[(size_t)g * NODE_PLANE_H2 + (size_t)v * 8 + p]);
    float pr[8];
#pragma unroll
    for (int c = 0; c < 8; c++) pr[c] = h.x * wreg[c] + h.y * wreg[8 + c];
#pragma unroll
    for (int c = 0; c < 8; c++) {
        float vsum = pr[c];
#pragma unroll
        for (int off = 32; off; off >>= 1) vsum += __shfl_xor(vsum, off);
        pr[c] = vsum;
    }
    float outv = pr[0];
#pragma unroll
    for (int c = 1; c < 8; c++) outv = (lane == c) ? pr[c] : outv;
    if (lane < 8) y2[(size_t)v * 8 + lane] = outv;
}

// ---------------- edge gather L2 (8 ch, fp32) ----------------
__global__ void k_egather2(const int* __restrict__ off_e, const int* __restrict__ list_e,
                           const float* __restrict__ y2, float* __restrict__ S2) {
    int t = blockIdx.x * blockDim.x + threadIdx.x;
    if (t >= N_HEDGES * 8) return;
    int e = t >> 3, c = t & 7;
    int s0 = off_e[e], s1 = off_e[e + 1];
    float acc = 0.f;
    for (int j = s0; j < s1; j++) {
        int u = list_e[j];
        acc += y2[u * 8 + c];
    }
    float binv = (s1 > s0) ? 1.f / (float)(s1 - s0) : 0.f;
    S2[e * 8 + c] = acc * binv;
}

// ---------------- node gather L2 (8 ch) ----------------
__global__ void k_ngather2(const int* __restrict__ off_n, const int* __restrict__ list_n,
                           const float* __restrict__ S2, const float* __restrict__ b2,
                           float* __restrict__ out) {
    int t = blockIdx.x * blockDim.x + threadIdx.x;
    if (t >= N_NODES * 8) return;
    int v = t >> 3, c = t & 7;
    int s0 = off_n[v], s1 = off_n[v + 1];
    float acc = 0.f;
    for (int j = s0; j < s1; j++) {
        int e = list_n[j];
        acc += S2[e * 8 + c];
    }
    float dinv = (s1 > s0) ? 1.f / (float)(s1 - s0) : 0.f;
    out[v * 8 + c] = fmaf(acc, dinv, b2[c]);
}

extern "C" void kernel_launch(void* const* d_in, const int* in_sizes, int n_in,
                              void* d_out, int out_size, void* d_ws, size_t ws_size,
                              hipStream_t stream) {
    const float* x   = (const float*)d_in[0];
    const int*   ei  = (const int*)d_in[1];     // [2, NNZ]: row0 = node_idx, row1 = edge_idx
    const float* W1  = (const float*)d_in[2];
    const float* b1  = (const float*)d_in[3];
    const float* W2  = (const float*)d_in[4];
    const float* b2  = (const float*)d_in[5];
    const int* nidx = ei;
    const int* eidx = ei + NNZ;

    // ---- workspace layout ----
    int* ip     = (int*)d_ws;
    int* deg_n  = ip;                        // 100000
    int* deg_e  = deg_n + N_NODES;           // 50000
    int* off_n  = deg_e + N_HEDGES;          // 100001
    int* off_e  = off_n + N_NODES + 1;       // 50001
    int* part   = off_e + N_HEDGES + 1;      // 64
    int* list_e = part + 64;                 // NNZ
    int* list_n = list_e + NNZ;              // NNZ
    int* rank_n = list_n + NNZ;              // NNZ
    int* rank_e = rank_n + NNZ;              // NNZ
    size_t int_count = (size_t)(rank_e + NNZ - ip);
    int_count = (int_count + 3) & ~(size_t)3;            // 16B align
    __half* xwh = (__half*)(ip + int_count);             // 8 planes x N_NODES*16
    __half* Sh  = xwh + (size_t)8 * N_NODES * 16;        // 8 planes x N_HEDGES*16
    __half* hh  = Sh  + (size_t)8 * N_HEDGES * 16;       // 8 planes x N_NODES*16
    float* fb   = (float*)(hh + (size_t)8 * N_NODES * 16);
    float* y2   = fb;                          // N_NODES*8
    float* S2   = y2 + (size_t)N_NODES * 8;    // N_HEDGES*8
    float* outp = (float*)d_out;

    hipMemsetAsync(deg_n, 0, (size_t)(N_NODES + N_HEDGES) * 4, stream);

    k_deg_gemm1<<<NB_MIX, 256, 0, stream>>>(nidx, eidx, deg_n, deg_e,
                                            rank_n, rank_e, x, W1, xwh);
    k_scan1<<<BE + BN, 1024, 0, stream>>>(deg_e, off_e, deg_n, off_n, part);
    k_scan2<<<1, 64, 0, stream>>>(part);
    k_scan3<<<BE + BN, 1024, 0, stream>>>(off_e, off_n, part);
    k_fill<<<(NNZ + 255) / 256, 256, 0, stream>>>(nidx, eidx, rank_n, rank_e,
                                                  off_n, off_e, list_n, list_e);
    k_egather1s<<<((N_HEDGES + 3) / 4) * 8, 256, 0, stream>>>(off_e, list_e,
                                                              (const __half2*)xwh, (__half2*)Sh);
    k_ngather1s<<<((N_NODES + 3) / 4) * 8, 256, 0, stream>>>(off_n, list_n,
                                                             (const __half2*)Sh, b1, (__half2*)hh);
    k_gemm2w<<<(N_NODES + 3) / 4, 256, 0, stream>>>((const __half2*)hh, W2, y2);
    k_egather2<<<(N_HEDGES * 8 + 255) / 256, 256, 0, stream>>>(off_e, list_e, y2, S2);
    k_ngather2<<<(N_NODES * 8 + 255) / 256, 256, 0, stream>>>(off_n, list_n, S2, b2, outp);
}

// Round 6
// 502.279 us; speedup vs baseline: 1.5901x; 1.5901x over previous
//
#include <hip/hip_runtime.h>
#include <hip/hip_bf16.h>
#include <hip/hip_fp16.h>

#define N_NODES  100000
#define N_HEDGES 50000
#define NNZ      1600000
#define IN_C     128
#define HID_C    128
#define N_CLS    8

#define BE 13   // ceil(N_HEDGES/4096)
#define BN 25   // ceil(N_NODES/4096)

#define NB_DEG ((NNZ + 255) / 256)      // 6250
#define NB_G1  ((N_NODES + 63) / 64)    // 1563
#define NB_MIX (NB_DEG + NB_G1)         // 7813

#define NB_FN   ((NNZ + 255) / 256)     // 6250 fill_n blocks
#define NB_EG   ((N_HEDGES + 3) / 4)    // 12500 egather blocks (4 waves each)
#define NB_MIX2 (NB_FN + NB_EG)         // 18750

// ---------------- merged (interleaved): degree+rank || GEMM1 (fp16 out) ----------------
__global__ __launch_bounds__(256) void k_deg_gemm1(
        const int* __restrict__ nidx, const int* __restrict__ eidx,
        int* __restrict__ deg_n, int* __restrict__ deg_e,
        int* __restrict__ rank_n, int* __restrict__ rank_e,
        const float* __restrict__ X, const float* __restrict__ W,
        __half* __restrict__ XWH) {
    __shared__ float sA[64 * 36];   // stride 36: 2-way LDS aliasing only (free)
    __shared__ float sB[32 * 128];
    const int bid = blockIdx.x;
    const bool is_gemm = (bid % 5 == 2);
    if (!is_gemm) {
        int deg_id = bid - (bid + 2) / 5;
        int i = deg_id * 256 + threadIdx.x;
        if (i < NNZ) {
            rank_n[i] = atomicAdd(&deg_n[nidx[i]], 1);
            rank_e[i] = atomicAdd(&deg_e[eidx[i]], 1);
        }
        return;
    }
    const int gid = (bid + 2) / 5;
    const int tid = threadIdx.x;
    const int row0 = gid * 64;
    const int tx = tid & 15, ty = tid >> 4;

    float acc[4][8];
#pragma unroll
    for (int r = 0; r < 4; r++)
#pragma unroll
        for (int c = 0; c < 8; c++) acc[r][c] = 0.f;

    for (int kt = 0; kt < 128; kt += 32) {
        {
            int idx = tid * 8;
            int ar = idx >> 5, ak = idx & 31;
            int grow = row0 + ar; if (grow >= N_NODES) grow = N_NODES - 1;
            const float4* src = (const float4*)&X[(size_t)grow * 128 + kt + ak];
            float4 v0 = src[0], v1 = src[1];
            *(float4*)&sA[ar * 36 + ak] = v0;
            *(float4*)&sA[ar * 36 + ak + 4] = v1;
        }
        {
            int idx = tid * 16;
            int br = idx >> 7, bc = idx & 127;
            const float4* src = (const float4*)&W[(size_t)(kt + br) * 128 + bc];
            float4 v0 = src[0], v1 = src[1], v2 = src[2], v3 = src[3];
            *(float4*)&sB[br * 128 + bc]      = v0;
            *(float4*)&sB[br * 128 + bc + 4]  = v1;
            *(float4*)&sB[br * 128 + bc + 8]  = v2;
            *(float4*)&sB[br * 128 + bc + 12] = v3;
        }
        __syncthreads();
#pragma unroll
        for (int kk = 0; kk < 32; kk++) {
            float a[4], b[8];
#pragma unroll
            for (int r = 0; r < 4; r++) a[r] = sA[(ty * 4 + r) * 36 + kk];
#pragma unroll
            for (int j = 0; j < 8; j++) b[j] = sB[kk * 128 + tx * 8 + j];
#pragma unroll
            for (int r = 0; r < 4; r++)
#pragma unroll
                for (int j = 0; j < 8; j++) acc[r][j] = fmaf(a[r], b[j], acc[r][j]);
        }
        __syncthreads();
    }
#pragma unroll
    for (int r = 0; r < 4; r++) {
        int grow = row0 + ty * 4 + r;
        if (grow < N_NODES) {
            __half2 p0 = __floats2half2_rn(acc[r][0], acc[r][1]);
            __half2 p1 = __floats2half2_rn(acc[r][2], acc[r][3]);
            __half2 p2 = __floats2half2_rn(acc[r][4], acc[r][5]);
            __half2 p3 = __floats2half2_rn(acc[r][6], acc[r][7]);
            __half2* dst = (__half2*)&XWH[(size_t)grow * 128 + tx * 8];
            dst[0] = p0; dst[1] = p1; dst[2] = p2; dst[3] = p3;
        }
    }
}

// ---------------- hierarchical scan, stage 1 ----------------
__global__ __launch_bounds__(1024) void k_scan1(const int* __restrict__ deg_e, int* __restrict__ off_e,
                                                const int* __restrict__ deg_n, int* __restrict__ off_n,
                                                int* __restrict__ part) {
    int gb = blockIdx.x;
    const int* cnt; int* off; int n; int b; int* ps;
    if (gb < BE) { cnt = deg_e; off = off_e; n = N_HEDGES; b = gb; ps = part; }
    else         { cnt = deg_n; off = off_n; n = N_NODES;  b = gb - BE; ps = part + 32; }
    const int tid = threadIdx.x, lane = tid & 63, wid = tid >> 6;
    int i0 = b * 4096 + tid * 4;
    int v0 = (i0 + 0 < n) ? cnt[i0 + 0] : 0;
    int v1 = (i0 + 1 < n) ? cnt[i0 + 1] : 0;
    int v2 = (i0 + 2 < n) ? cnt[i0 + 2] : 0;
    int v3 = (i0 + 3 < n) ? cnt[i0 + 3] : 0;
    int s = v0 + v1 + v2 + v3;
    int incl = s;
#pragma unroll
    for (int d = 1; d < 64; d <<= 1) {
        int t = __shfl_up(incl, d);
        if (lane >= d) incl += t;
    }
    __shared__ int wsum[16];
    __shared__ int wbase[16];
    if (lane == 63) wsum[wid] = incl;
    __syncthreads();
    if (tid == 0) {
        int r = 0;
#pragma unroll
        for (int k = 0; k < 16; k++) { wbase[k] = r; r += wsum[k]; }
        ps[b] = r;
    }
    __syncthreads();
    int run = wbase[wid] + incl - s;
    if (i0 + 0 < n) { run += v0; off[i0 + 1] = run; }
    if (i0 + 1 < n) { run += v1; off[i0 + 2] = run; }
    if (i0 + 2 < n) { run += v2; off[i0 + 3] = run; }
    if (i0 + 3 < n) { run += v3; off[i0 + 4] = run; }
}

// ---------------- stage 2 ----------------
__global__ void k_scan2(int* __restrict__ part) {
    int t = threadIdx.x;
    if (t == 0) { int r = 0; for (int k = 0; k < BE; k++) { int x = part[k]; part[k] = r; r += x; } }
    if (t == 1) { int r = 0; for (int k = 0; k < BN; k++) { int x = part[32 + k]; part[32 + k] = r; r += x; } }
}

// ---------------- stage 3 ----------------
__global__ __launch_bounds__(1024) void k_scan3(int* __restrict__ off_e, int* __restrict__ off_n,
                                                const int* __restrict__ part) {
    int gb = blockIdx.x;
    int* off; int n; int b; int add;
    if (gb < BE) { off = off_e; n = N_HEDGES; b = gb; add = part[b]; }
    else         { off = off_n; n = N_NODES;  b = gb - BE; add = part[32 + b]; }
    int tid = threadIdx.x;
    int i0 = b * 4096 + tid * 4;
    if (b == 0 && tid == 0) off[0] = 0;
#pragma unroll
    for (int k = 0; k < 4; k++)
        if (i0 + k < n) off[i0 + 1 + k] += add;
}

// ---------------- fill list_e only ----------------
__global__ void k_fill_e(const int* __restrict__ nidx, const int* __restrict__ eidx,
                         const int* __restrict__ rank_e, const int* __restrict__ off_e,
                         int* __restrict__ list_e) {
    int i = blockIdx.x * blockDim.x + threadIdx.x;
    if (i < NNZ) {
        list_e[off_e[eidx[i]] + rank_e[i]] = nidx[i];
    }
}

// ---------------- merged (interleaved): fill list_n || edge gather L1 (fp16) ----------------
// S[e] = Binv[e] * sum_{v in e} xw[v]   (wave/edge, 64 lanes x half2 = 128 ch)
__global__ __launch_bounds__(256) void k_filln_egather1(
        const int* __restrict__ nidx, const int* __restrict__ eidx,
        const int* __restrict__ rank_n, const int* __restrict__ off_n,
        int* __restrict__ list_n,
        const int* __restrict__ off_e, const int* __restrict__ list_e,
        const __half2* __restrict__ xw2, __half2* __restrict__ S2h) {
    const int bid = blockIdx.x;
    if (bid % 3 == 0) {
        int i = (bid / 3) * 256 + threadIdx.x;
        if (i < NNZ) {
            list_n[off_n[nidx[i]] + rank_n[i]] = eidx[i];
        }
        return;
    }
    const int eb = bid - bid / 3 - 1;
    const int w = eb * 4 + (threadIdx.x >> 6);
    const int lane = threadIdx.x & 63;
    if (w >= N_HEDGES) return;
    int s0 = off_e[w], s1 = off_e[w + 1];
    float ax = 0.f, ay = 0.f;
    for (int base = s0; base < s1; base += 64) {
        int rem = s1 - base;
        int cnt = rem > 64 ? 64 : rem;
        int idx = (lane < cnt) ? list_e[base + lane] : 0;
        int j = 0;
        for (; j + 4 <= cnt; j += 4) {
            int u0 = __shfl(idx, j + 0), u1 = __shfl(idx, j + 1);
            int u2 = __shfl(idx, j + 2), u3 = __shfl(idx, j + 3);
            float2 t0 = __half22float2(xw2[(size_t)u0 * 64 + lane]);
            float2 t1 = __half22float2(xw2[(size_t)u1 * 64 + lane]);
            float2 t2 = __half22float2(xw2[(size_t)u2 * 64 + lane]);
            float2 t3 = __half22float2(xw2[(size_t)u3 * 64 + lane]);
            ax += t0.x + t1.x; ay += t0.y + t1.y;
            ax += t2.x + t3.x; ay += t2.y + t3.y;
        }
        for (; j < cnt; j++) {
            int u = __shfl(idx, j);
            float2 t = __half22float2(xw2[(size_t)u * 64 + lane]);
            ax += t.x; ay += t.y;
        }
    }
    float binv = (s1 > s0) ? 1.f / (float)(s1 - s0) : 0.f;
    S2h[(size_t)w * 64 + lane] = __floats2half2_rn(ax * binv, ay * binv);
}

// ---------------- node gather L1 (fp16) fused with GEMM2 ----------------
__global__ __launch_bounds__(256) void k_ngather1g(const int* __restrict__ off_n,
                                                   const int* __restrict__ list_n,
                                                   const __half2* __restrict__ S2h,
                                                   const float* __restrict__ b1,
                                                   const float* __restrict__ W2,
                                                   float* __restrict__ y2) {
    int w = (blockIdx.x * 256 + threadIdx.x) >> 6;
    int lane = threadIdx.x & 63;
    if (w >= N_NODES) return;
    float wreg[16];
    {
        const float4* wp = (const float4*)&W2[16 * lane];
#pragma unroll
        for (int q = 0; q < 4; q++) {
            float4 t = wp[q];
            wreg[4 * q + 0] = t.x; wreg[4 * q + 1] = t.y;
            wreg[4 * q + 2] = t.z; wreg[4 * q + 3] = t.w;
        }
    }
    int s0 = off_n[w], s1 = off_n[w + 1];
    float ax = 0.f, ay = 0.f;
    for (int base = s0; base < s1; base += 64) {
        int rem = s1 - base;
        int cnt = rem > 64 ? 64 : rem;
        int idx = (lane < cnt) ? list_n[base + lane] : 0;
        int j = 0;
        for (; j + 4 <= cnt; j += 4) {
            int e0 = __shfl(idx, j + 0), e1 = __shfl(idx, j + 1);
            int e2 = __shfl(idx, j + 2), e3 = __shfl(idx, j + 3);
            float2 t0 = __half22float2(S2h[(size_t)e0 * 64 + lane]);
            float2 t1 = __half22float2(S2h[(size_t)e1 * 64 + lane]);
            float2 t2 = __half22float2(S2h[(size_t)e2 * 64 + lane]);
            float2 t3 = __half22float2(S2h[(size_t)e3 * 64 + lane]);
            ax += t0.x + t1.x; ay += t0.y + t1.y;
            ax += t2.x + t3.x; ay += t2.y + t3.y;
        }
        for (; j < cnt; j++) {
            int e = __shfl(idx, j);
            float2 t = __half22float2(S2h[(size_t)e * 64 + lane]);
            ax += t.x; ay += t.y;
        }
    }
    float dinv = (s1 > s0) ? 1.f / (float)(s1 - s0) : 0.f;
    float2 bb = *(const float2*)&b1[lane * 2];
    float h0 = fmaxf(fmaf(ax, dinv, bb.x), 0.f);
    float h1 = fmaxf(fmaf(ay, dinv, bb.y), 0.f);
    float p[8];
#pragma unroll
    for (int c = 0; c < 8; c++) p[c] = h0 * wreg[c] + h1 * wreg[8 + c];
#pragma unroll
    for (int c = 0; c < 8; c++) {
        float vsum = p[c];
#pragma unroll
        for (int off = 32; off; off >>= 1) vsum += __shfl_xor(vsum, off);
        p[c] = vsum;
    }
    float outv = p[0];
#pragma unroll
    for (int c = 1; c < 8; c++) outv = (lane == c) ? p[c] : outv;
    if (lane < 8) y2[(size_t)w * 8 + lane] = outv;
}

// ---------------- edge gather L2 (8 ch, fp32) ----------------
__global__ void k_egather2(const int* __restrict__ off_e, const int* __restrict__ list_e,
                           const float* __restrict__ y2, float* __restrict__ S2) {
    int t = blockIdx.x * blockDim.x + threadIdx.x;
    if (t >= N_HEDGES * 8) return;
    int e = t >> 3, c = t & 7;
    int s0 = off_e[e], s1 = off_e[e + 1];
    float acc = 0.f;
    for (int j = s0; j < s1; j++) {
        int u = list_e[j];
        acc += y2[u * 8 + c];
    }
    float binv = (s1 > s0) ? 1.f / (float)(s1 - s0) : 0.f;
    S2[e * 8 + c] = acc * binv;
}

// ---------------- node gather L2 (8 ch) ----------------
__global__ void k_ngather2(const int* __restrict__ off_n, const int* __restrict__ list_n,
                           const float* __restrict__ S2, const float* __restrict__ b2,
                           float* __restrict__ out) {
    int t = blockIdx.x * blockDim.x + threadIdx.x;
    if (t >= N_NODES * 8) return;
    int v = t >> 3, c = t & 7;
    int s0 = off_n[v], s1 = off_n[v + 1];
    float acc = 0.f;
    for (int j = s0; j < s1; j++) {
        int e = list_n[j];
        acc += S2[e * 8 + c];
    }
    float dinv = (s1 > s0) ? 1.f / (float)(s1 - s0) : 0.f;
    out[v * 8 + c] = fmaf(acc, dinv, b2[c]);
}

extern "C" void kernel_launch(void* const* d_in, const int* in_sizes, int n_in,
                              void* d_out, int out_size, void* d_ws, size_t ws_size,
                              hipStream_t stream) {
    const float* x   = (const float*)d_in[0];
    const int*   ei  = (const int*)d_in[1];     // [2, NNZ]: row0 = node_idx, row1 = edge_idx
    const float* W1  = (const float*)d_in[2];
    const float* b1  = (const float*)d_in[3];
    const float* W2  = (const float*)d_in[4];
    const float* b2  = (const float*)d_in[5];
    const int* nidx = ei;
    const int* eidx = ei + NNZ;

    // ---- workspace layout ----
    int* ip     = (int*)d_ws;
    int* deg_n  = ip;                        // 100000
    int* deg_e  = deg_n + N_NODES;           // 50000
    int* off_n  = deg_e + N_HEDGES;          // 100001
    int* off_e  = off_n + N_NODES + 1;       // 50001
    int* part   = off_e + N_HEDGES + 1;      // 64
    int* list_e = part + 64;                 // NNZ
    int* list_n = list_e + NNZ;              // NNZ
    int* rank_n = list_n + NNZ;              // NNZ
    int* rank_e = rank_n + NNZ;              // NNZ
    size_t int_count = (size_t)(rank_e + NNZ - ip);
    int_count = (int_count + 3) & ~(size_t)3;            // 16B align
    __half* xwh = (__half*)(ip + int_count);             // N_NODES*128 fp16 (25.6 MB)
    __half* Sh  = xwh + (size_t)N_NODES * 128;           // N_HEDGES*128 fp16 (12.8 MB)
    float* fb   = (float*)(Sh + (size_t)N_HEDGES * 128);
    float* y2   = fb;                          // N_NODES*8
    float* S2   = y2 + (size_t)N_NODES * 8;    // N_HEDGES*8
    float* outp = (float*)d_out;

    hipMemsetAsync(deg_n, 0, (size_t)(N_NODES + N_HEDGES) * 4, stream);

    k_deg_gemm1<<<NB_MIX, 256, 0, stream>>>(nidx, eidx, deg_n, deg_e,
                                            rank_n, rank_e, x, W1, xwh);
    k_scan1<<<BE + BN, 1024, 0, stream>>>(deg_e, off_e, deg_n, off_n, part);
    k_scan2<<<1, 64, 0, stream>>>(part);
    k_scan3<<<BE + BN, 1024, 0, stream>>>(off_e, off_n, part);
    k_fill_e<<<(NNZ + 255) / 256, 256, 0, stream>>>(nidx, eidx, rank_e, off_e, list_e);
    k_filln_egather1<<<NB_MIX2, 256, 0, stream>>>(nidx, eidx, rank_n, off_n, list_n,
                                                  off_e, list_e,
                                                  (const __half2*)xwh, (__half2*)Sh);
    k_ngather1g<<<(N_NODES * 64 + 255) / 256, 256, 0, stream>>>(off_n, list_n,
                                                                (const __half2*)Sh, b1, W2, y2);
    k_egather2<<<(N_HEDGES * 8 + 255) / 256, 256, 0, stream>>>(off_e, list_e, y2, S2);
    k_ngather2<<<(N_NODES * 8 + 255) / 256, 256, 0, stream>>>(off_n, list_n, S2, b2, outp);
}